// Round 1
// baseline (960.004 us; speedup 1.0000x reference)
//
#include <hip/hip_runtime.h>

typedef _Float16 half_t;
typedef _Float16 f16x8 __attribute__((ext_vector_type(8)));
typedef _Float16 f16x4 __attribute__((ext_vector_type(4)));
typedef float    f32x4 __attribute__((ext_vector_type(4)));

#define BB 32
#define LP 2048
#define LQ 512
#define HH 1024

enum { M_QPROJ = 0, M_ATT = 1, M_MP = 2, M_MQ = 3 };

// ---------------- W f32 -> f16 ----------------
__global__ void cvt_w_k(const float* __restrict__ w, half_t* __restrict__ o) {
  long i = ((long)blockIdx.x * 256 + threadIdx.x) * 4;
  f32x4 v = *(const f32x4*)(w + i);
  f16x4 h;
  h[0] = (half_t)v[0]; h[1] = (half_t)v[1]; h[2] = (half_t)v[2]; h[3] = (half_t)v[3];
  *(f16x4*)(o + i) = h;
}

// ---------------- row softmax stats (over LQ=512), one wave per row ----------------
__global__ __launch_bounds__(256) void rstats_k(const float* __restrict__ att,
                                                float* __restrict__ rmax,
                                                float* __restrict__ rinv) {
  int lane = threadIdx.x & 63;
  long row = (long)blockIdx.x * 4 + (threadIdx.x >> 6);
  const float* src = att + row * LQ + lane * 8;
  f32x4 a = *(const f32x4*)src;
  f32x4 c = *(const f32x4*)(src + 4);
  float m = fmaxf(fmaxf(fmaxf(a[0], a[1]), fmaxf(a[2], a[3])),
                  fmaxf(fmaxf(c[0], c[1]), fmaxf(c[2], c[3])));
#pragma unroll
  for (int o = 32; o > 0; o >>= 1) m = fmaxf(m, __shfl_xor(m, o, 64));
  float s = 0.f;
#pragma unroll
  for (int j = 0; j < 4; j++) s += __expf(a[j] - m) + __expf(c[j] - m);
#pragma unroll
  for (int o = 32; o > 0; o >>= 1) s += __shfl_xor(s, o, 64);
  if (lane == 0) { rmax[row] = m; rinv[row] = 1.f / s; }
}

// ---------------- col softmax stats (over LP=2048) ----------------
__global__ __launch_bounds__(256) void cstats_k(const float* __restrict__ att,
                                                float* __restrict__ cmax,
                                                float* __restrict__ cinv) {
  int b = blockIdx.y;
  int ql = threadIdx.x & 63;
  int q = blockIdx.x * 64 + ql;
  int strip = threadIdx.x >> 6;
  const float* src = att + (long)b * LP * LQ + q;
  float m = -3e38f, s = 0.f;
  for (int p = strip; p < LP; p += 4) {
    float x = src[(long)p * LQ];
    float nm = fmaxf(m, x);
    s = s * __expf(m - nm) + __expf(x - nm);
    m = nm;
  }
  __shared__ float sm[4][64], ss[4][64];
  sm[strip][ql] = m; ss[strip][ql] = s;
  __syncthreads();
  if (threadIdx.x < 64) {
    float M = sm[0][ql];
#pragma unroll
    for (int k = 1; k < 4; k++) M = fmaxf(M, sm[k][ql]);
    float S = 0.f;
#pragma unroll
    for (int k = 0; k < 4; k++) S += ss[k][ql] * __expf(sm[k][ql] - M);
    cmax[(long)b * LQ + q] = M;
    cinv[(long)b * LQ + q] = 1.f / S;
  }
}

// ---------------- unified tiled MFMA GEMM ----------------
// 128x128 tile, BK=32, 256 threads (4 waves, 2x2), wave computes 64x64.
// A staged as As[row][k], B staged as Bs[col][k] (both K-contiguous in LDS).
template<int MODE>
__global__ __launch_bounds__(256) void gemm_k(
    const void* __restrict__ Ap, const void* __restrict__ Bp, void* __restrict__ Cp,
    const float* __restrict__ bias, const float* __restrict__ smax, const float* __restrict__ sinv,
    int lda, int ldb, int ldc, int K,
    long sA, long sB, long sC, int sStat) {
  __shared__ __align__(16) half_t As[128][40];  // +8 pad: 80B rows -> 2-way max on frag reads
  __shared__ __align__(16) half_t Bs[128][40];

  const int t = threadIdx.x;
  const int lane = t & 63;
  const int wid = t >> 6;
  const int wm = (wid >> 1) * 64, wn = (wid & 1) * 64;
  const int m0 = blockIdx.y * 128, n0 = blockIdx.x * 128;
  const int b = blockIdx.z;

  f32x4 acc[4][4] = {};

  // loader thread mappings
  const int a_row = t >> 1, a_kq = (t & 1) * 16;        // row-major A (QPROJ/ATT/MP)
  const int a_kp = t >> 3, a_qq = (t & 7) * 16;         // transposed A (MQ)
  const int b_row = t >> 1, b_kq = (t & 1) * 16;        // BT f16 B
  const int b_ng = (t & 31) * 4, b_kg = (t >> 5) * 4;   // NN f32 B (transpose-stage)

  float rm = 0.f, ri = 1.f;
  float cmv[16], civ[16];
  if constexpr (MODE == M_MP) {
    rm = smax[(long)sStat * b + m0 + a_row];
    ri = sinv[(long)sStat * b + m0 + a_row];
  }
  if constexpr (MODE == M_MQ) {
#pragma unroll
    for (int j = 0; j < 16; j++) {
      cmv[j] = smax[(long)sStat * b + m0 + a_qq + j];
      civ[j] = sinv[(long)sStat * b + m0 + a_qq + j];
    }
  }

  const float* Af = (const float*)Ap;
  const half_t* Bh = (const half_t*)Bp;
  const float* Bf = (const float*)Bp;

  for (int k0 = 0; k0 < K; k0 += 32) {
    // ---- stage A ----
    if constexpr (MODE == M_MQ) {
      // A[q][p] = exp(att[p][q] - cmax[q]) * cinv[q]  (transpose in loader)
      const float* src = Af + sA * b + (long)(k0 + a_kp) * lda + (m0 + a_qq);
#pragma unroll
      for (int i = 0; i < 4; i++) {
        f32x4 v = *(const f32x4*)(src + 4 * i);
#pragma unroll
        for (int j = 0; j < 4; j++) {
          int jj = 4 * i + j;
          As[a_qq + jj][a_kp] = (half_t)(__expf(v[j] - cmv[jj]) * civ[jj]);
        }
      }
    } else {
      const float* src = Af + sA * b + (long)(m0 + a_row) * lda + k0 + a_kq;
      float x[16];
#pragma unroll
      for (int i = 0; i < 4; i++) {
        f32x4 v = *(const f32x4*)(src + 4 * i);
        x[4 * i + 0] = v[0]; x[4 * i + 1] = v[1];
        x[4 * i + 2] = v[2]; x[4 * i + 3] = v[3];
      }
      f16x8 h0, h1;
#pragma unroll
      for (int j = 0; j < 8; j++) {
        float v0 = x[j], v1 = x[8 + j];
        if constexpr (MODE == M_MP) {
          v0 = __expf(v0 - rm) * ri;
          v1 = __expf(v1 - rm) * ri;
        }
        h0[j] = (half_t)v0; h1[j] = (half_t)v1;
      }
      *(f16x8*)&As[a_row][a_kq]     = h0;
      *(f16x8*)&As[a_row][a_kq + 8] = h1;
    }
    // ---- stage B ----
    if constexpr (MODE == M_QPROJ || MODE == M_ATT) {
      const half_t* src = Bh + sB * b + (long)(n0 + b_row) * ldb + k0 + b_kq;
      *(f16x8*)&Bs[b_row][b_kq]     = *(const f16x8*)src;
      *(f16x8*)&Bs[b_row][b_kq + 8] = *(const f16x8*)(src + 8);
    } else {
      // B global [K, N] f32 -> LDS [n][k] with convert (4x4 micro-transpose)
      const float* src = Bf + sB * b + (long)(k0 + b_kg) * ldb + n0 + b_ng;
      f32x4 v[4];
#pragma unroll
      for (int i = 0; i < 4; i++) v[i] = *(const f32x4*)(src + (long)i * ldb);
#pragma unroll
      for (int j = 0; j < 4; j++) {
        f16x4 w;
        w[0] = (half_t)v[0][j]; w[1] = (half_t)v[1][j];
        w[2] = (half_t)v[2][j]; w[3] = (half_t)v[3][j];
        *(f16x4*)&Bs[b_ng + j][b_kg] = w;
      }
    }
    __syncthreads();

    // ---- fragments + MFMA ----
    {
      const int fr = lane & 15, fg = (lane >> 4) * 8;
      f16x8 af[4], bfr[4];
#pragma unroll
      for (int f = 0; f < 4; f++) af[f]  = *(const f16x8*)&As[wm + f * 16 + fr][fg];
#pragma unroll
      for (int f = 0; f < 4; f++) bfr[f] = *(const f16x8*)&Bs[wn + f * 16 + fr][fg];
#pragma unroll
      for (int fm = 0; fm < 4; fm++)
#pragma unroll
        for (int fn = 0; fn < 4; fn++)
          acc[fm][fn] = __builtin_amdgcn_mfma_f32_16x16x32_f16(af[fm], bfr[fn], acc[fm][fn], 0, 0, 0);
    }
    __syncthreads();
  }

  // ---- epilogue: D row=(l>>4)*4+j, col=l&15 (verified C/D layout) ----
  const int fr = lane & 15, r0 = (lane >> 4) * 4;
#pragma unroll
  for (int fn = 0; fn < 4; fn++) {
    int col = n0 + wn + fn * 16 + fr;
    float bv = 0.f;
    if constexpr (MODE == M_QPROJ) bv = bias[col];
#pragma unroll
    for (int fm = 0; fm < 4; fm++) {
      int row = m0 + wm + fm * 16 + r0;
#pragma unroll
      for (int j = 0; j < 4; j++) {
        float v = acc[fm][fn][j];
        if constexpr (MODE == M_QPROJ) {
          ((half_t*)Cp)[(long)(row + j) * ldc + col] = (half_t)(v + bv);
        } else {
          ((float*)Cp)[sC * b + (long)(row + j) * ldc + col] = v;
        }
      }
    }
  }
}

extern "C" void kernel_launch(void* const* d_in, const int* in_sizes, int n_in,
                              void* d_out, int out_size, void* d_ws, size_t ws_size,
                              hipStream_t stream) {
  const float* p_enc = (const float*)d_in[0];  // [B, LP, H]
  const float* q_enc = (const float*)d_in[1];  // [B, LQ, H]
  const float* Gw    = (const float*)d_in[2];  // [H, H]
  const float* Gb    = (const float*)d_in[3];  // [H]
  float* m_p = (float*)d_out;                  // [B, LP, H]
  float* m_q = m_p + (long)BB * LP * HH;       // [B, LQ, H]

  // workspace carve (~170.5 MB)
  half_t* w16     = (half_t*)d_ws;                          // H*H f16
  half_t* qproj16 = w16 + (long)HH * HH;                    // B*LQ*H f16
  float*  att     = (float*)(qproj16 + (long)BB * LQ * HH); // B*LP*LQ f32
  float*  rmaxb   = att + (long)BB * LP * LQ;               // B*LP
  float*  rinvb   = rmaxb + (long)BB * LP;
  float*  cmaxb   = rinvb + (long)BB * LP;                  // B*LQ
  float*  cinvb   = cmaxb + (long)BB * LQ;

  cvt_w_k<<<dim3(HH * HH / 1024), 256, 0, stream>>>(Gw, w16);

  // q_proj[bq, o] = q_enc[bq, :] . Gw[o, :] + Gb[o]   (M=B*LQ, N=H, K=H)
  gemm_k<M_QPROJ><<<dim3(HH / 128, (BB * LQ) / 128, 1), 256, 0, stream>>>(
      q_enc, w16, qproj16, Gb, nullptr, nullptr,
      HH, HH, HH, HH, 0, 0, 0, 0);

  // att[b][p][q] = p_enc[b,p,:] . q_proj[b,q,:]   (M=LP, N=LQ, K=H)
  gemm_k<M_ATT><<<dim3(LQ / 128, LP / 128, BB), 256, 0, stream>>>(
      p_enc, qproj16, att, nullptr, nullptr, nullptr,
      HH, HH, LQ, HH, (long)LP * HH, (long)LQ * HH, (long)LP * LQ, 0);

  rstats_k<<<dim3(BB * LP / 4), 256, 0, stream>>>(att, rmaxb, rinvb);
  cstats_k<<<dim3(LQ / 64, BB), 256, 0, stream>>>(att, cmaxb, cinvb);

  // m_p[b][p][h] = sum_q softmax_row(att)[p][q] * q_enc[b][q][h]  (M=LP, N=H, K=LQ)
  gemm_k<M_MP><<<dim3(HH / 128, LP / 128, BB), 256, 0, stream>>>(
      att, q_enc, m_p, nullptr, rmaxb, rinvb,
      LQ, HH, HH, LQ, (long)LP * LQ, (long)LQ * HH, (long)LP * HH, LP);

  // m_q[b][q][h] = sum_p softmax_col(att)[p][q] * p_enc[b][p][h]  (M=LQ, N=H, K=LP)
  gemm_k<M_MQ><<<dim3(HH / 128, LQ / 128, BB), 256, 0, stream>>>(
      att, p_enc, m_q, nullptr, cmaxb, cinvb,
      LQ, HH, HH, LP, (long)LP * LQ, (long)LP * HH, (long)LQ * HH, LQ);
}

// Round 2
// 910.804 us; speedup vs baseline: 1.0540x; 1.0540x over previous
//
#include <hip/hip_runtime.h>

typedef _Float16 half_t;
typedef _Float16 f16x8 __attribute__((ext_vector_type(8)));
typedef _Float16 f16x4 __attribute__((ext_vector_type(4)));
typedef float    f32x4 __attribute__((ext_vector_type(4)));

#define BB 32
#define LP 2048
#define LQ 512
#define HH 1024

enum { M_QPROJ = 0, M_ATT = 1, M_F16 = 2 };

// ---------------- W f32 -> f16 (same layout) ----------------
__global__ void cvt_w_k(const float* __restrict__ w, half_t* __restrict__ o) {
  long i = ((long)blockIdx.x * 256 + threadIdx.x) * 4;
  f32x4 v = *(const f32x4*)(w + i);
  f16x4 h;
  h[0] = (half_t)v[0]; h[1] = (half_t)v[1]; h[2] = (half_t)v[2]; h[3] = (half_t)v[3];
  *(f16x4*)(o + i) = h;
}

// ---------------- tiled transpose + cvt (+optional col-exp) ----------------
// in [z][R][C] f32 -> out [z][C][R] f16 ; if EXP: x = exp(x - smax[z][c]) * sinv[z][c]
template<bool EXP>
__global__ __launch_bounds__(256) void tr_cvt_k(const float* __restrict__ in,
                                                half_t* __restrict__ out,
                                                const float* __restrict__ smax,
                                                const float* __restrict__ sinv,
                                                int R, int C) {
  __shared__ half_t tile[64 * 64];
  const long zb = blockIdx.z;
  const float* src = in + zb * (long)R * C;
  half_t* dst = out + zb * (long)C * R;
  const int r0 = blockIdx.y * 64, c0 = blockIdx.x * 64;
  const int t = threadIdx.x;
  const int cl = (t & 15) * 4;  // 4 cols per thread
  const int rl = t >> 4;        // base row 0..15

  float cm[4], ci[4];
  if constexpr (EXP) {
    f32x4 a = *(const f32x4*)(smax + zb * C + c0 + cl);
    f32x4 bvec = *(const f32x4*)(sinv + zb * C + c0 + cl);
#pragma unroll
    for (int j = 0; j < 4; j++) { cm[j] = a[j]; ci[j] = bvec[j]; }
  }
#pragma unroll
  for (int rr = 0; rr < 4; rr++) {
    int r = rr * 16 + rl;
    f32x4 v = *(const f32x4*)(src + (long)(r0 + r) * C + c0 + cl);
#pragma unroll
    for (int j = 0; j < 4; j++) {
      float x = v[j];
      if constexpr (EXP) x = __expf(x - cm[j]) * ci[j];
      int c = cl + j;
      tile[c * 64 + (r ^ (((c >> 3) & 7) << 3))] = (half_t)x;  // XOR-swizzled store
    }
  }
  __syncthreads();
  // each thread: one col c, 16 consecutive r
  const int c = t >> 2;
  const int rch = (t & 3) * 16;
  const int m = (c >> 3) & 7;
  const int B0 = c * 64 + (rch ^ ((m << 3) & 48));
  const int hi = (m & 1) << 3;
  f16x8 g0 = *(const f16x8*)&tile[B0 + hi];        // r = rch+0..7
  f16x8 g1 = *(const f16x8*)&tile[B0 + (8 ^ hi)];  // r = rch+8..15
  half_t* dp = dst + (long)(c0 + c) * R + r0 + rch;
  *(f16x8*)dp = g0;
  *(f16x8*)(dp + 8) = g1;
}

// ---------------- fused row softmax + normalize -> f16 (row length = NV*256) ----------------
template<int NV>
__global__ __launch_bounds__(256) void rownorm_k(const float* __restrict__ in,
                                                 half_t* __restrict__ out) {
  const int lane = threadIdx.x & 63;
  const long row = (long)blockIdx.x * 4 + (threadIdx.x >> 6);
  const int L = NV * 256;
  const float* src = in + row * L;
  f32x4 v[NV];
#pragma unroll
  for (int i = 0; i < NV; i++) v[i] = *(const f32x4*)(src + i * 256 + lane * 4);
  float m = -3e38f;
#pragma unroll
  for (int i = 0; i < NV; i++)
    m = fmaxf(m, fmaxf(fmaxf(v[i][0], v[i][1]), fmaxf(v[i][2], v[i][3])));
#pragma unroll
  for (int o = 32; o > 0; o >>= 1) m = fmaxf(m, __shfl_xor(m, o, 64));
  float s = 0.f;
#pragma unroll
  for (int i = 0; i < NV; i++)
#pragma unroll
    for (int j = 0; j < 4; j++) { v[i][j] = __expf(v[i][j] - m); s += v[i][j]; }
#pragma unroll
  for (int o = 32; o > 0; o >>= 1) s += __shfl_xor(s, o, 64);
  const float inv = 1.f / s;
  half_t* dst = out + row * L;
#pragma unroll
  for (int i = 0; i < NV; i++) {
    f16x4 h;
#pragma unroll
    for (int j = 0; j < 4; j++) h[j] = (half_t)(v[i][j] * inv);
    *(f16x4*)(dst + i * 256 + lane * 4) = h;
  }
}

// ---------------- col softmax stats (over LP) ----------------
__global__ __launch_bounds__(256) void cstats_k(const float* __restrict__ att,
                                                float* __restrict__ cmax,
                                                float* __restrict__ cinv) {
  const int b = blockIdx.y;
  const int ql = threadIdx.x & 63;
  const int q = blockIdx.x * 64 + ql;
  const int strip = threadIdx.x >> 6;
  const float* src = att + (long)b * LP * LQ + q;
  float m = -3e38f, s = 0.f;
  for (int p = strip; p < LP; p += 4) {
    float x = src[(long)p * LQ];
    float nm = fmaxf(m, x);
    s = s * __expf(m - nm) + __expf(x - nm);
    m = nm;
  }
  __shared__ float sm[4][64], ss[4][64];
  sm[strip][ql] = m; ss[strip][ql] = s;
  __syncthreads();
  if (threadIdx.x < 64) {
    float M = sm[0][ql];
#pragma unroll
    for (int k = 1; k < 4; k++) M = fmaxf(M, sm[k][ql]);
    float S = 0.f;
#pragma unroll
    for (int k = 0; k < 4; k++) S += ss[k][ql] * __expf(sm[k][ql] - M);
    cmax[(long)b * LQ + q] = M;
    cinv[(long)b * LQ + q] = 1.f / S;
  }
}

// ---------------- unified TN MFMA GEMM, 128x128 tile, BK=32 ----------------
template<int MODE>
__global__ __launch_bounds__(256) void gemm_k(
    const void* __restrict__ Ap, const half_t* __restrict__ Bp, void* __restrict__ Cp,
    const float* __restrict__ bias,
    int lda, int ldb, int ldc, int K,
    long sA, long sB, long sC) {
  __shared__ __align__(16) half_t As[128][40];
  __shared__ __align__(16) half_t Bs[128][40];

  const int t = threadIdx.x;
  const int lane = t & 63;
  const int wid = t >> 6;
  const int wm = (wid >> 1) * 64, wn = (wid & 1) * 64;
  const int m0 = blockIdx.y * 128, n0 = blockIdx.x * 128;
  const int b = blockIdx.z;

  f32x4 acc[4][4] = {};

  const int s_row = t >> 2, s_kq = (t & 3) * 8;  // f16 stage: 64B/row bursts
  const int f_row = t >> 3, f_c  = (t & 7) * 4;  // f32 stage: 128B/row bursts

  const half_t* A16 = (const half_t*)Ap + sA * b;
  const float*  A32 = (const float*)Ap  + sA * b;
  const half_t* B16 = Bp + sB * b;

  const int fr = lane & 15, fg = (lane >> 4) * 8;

  for (int k0 = 0; k0 < K; k0 += 32) {
    // ---- stage A ----
    if constexpr (MODE == M_F16) {
#pragma unroll
      for (int p = 0; p < 128; p += 64) {
        int row = s_row + p;
        *(f16x8*)&As[row][s_kq] =
            *(const f16x8*)(A16 + (long)(m0 + row) * lda + k0 + s_kq);
      }
    } else {
#pragma unroll
      for (int p = 0; p < 128; p += 32) {
        int row = f_row + p;
        f32x4 v = *(const f32x4*)(A32 + (long)(m0 + row) * lda + k0 + f_c);
        f16x4 h;
        h[0] = (half_t)v[0]; h[1] = (half_t)v[1];
        h[2] = (half_t)v[2]; h[3] = (half_t)v[3];
        *(f16x4*)&As[row][f_c] = h;
      }
    }
    // ---- stage B (f16 row-major, K-contiguous) ----
#pragma unroll
    for (int p = 0; p < 128; p += 64) {
      int row = s_row + p;
      *(f16x8*)&Bs[row][s_kq] =
          *(const f16x8*)(B16 + (long)(n0 + row) * ldb + k0 + s_kq);
    }
    __syncthreads();

    f16x8 af[4], bf[4];
#pragma unroll
    for (int f = 0; f < 4; f++) af[f] = *(const f16x8*)&As[wm + f * 16 + fr][fg];
#pragma unroll
    for (int f = 0; f < 4; f++) bf[f] = *(const f16x8*)&Bs[wn + f * 16 + fr][fg];
#pragma unroll
    for (int fm = 0; fm < 4; fm++)
#pragma unroll
      for (int fn = 0; fn < 4; fn++)
        acc[fm][fn] = __builtin_amdgcn_mfma_f32_16x16x32_f16(af[fm], bf[fn], acc[fm][fn], 0, 0, 0);
    __syncthreads();
  }

  // ---- epilogue: D row=(lane>>4)*4+j, col=lane&15 ----
  const int r0 = (lane >> 4) * 4;
#pragma unroll
  for (int fn = 0; fn < 4; fn++) {
    int col = n0 + wn + fn * 16 + fr;
    float bv = 0.f;
    if constexpr (MODE == M_QPROJ) bv = bias[col];
#pragma unroll
    for (int fm = 0; fm < 4; fm++) {
      int row = m0 + wm + fm * 16 + r0;
#pragma unroll
      for (int j = 0; j < 4; j++) {
        if constexpr (MODE == M_QPROJ)
          ((half_t*)Cp)[(long)(row + j) * ldc + col] = (half_t)(acc[fm][fn][j] + bv);
        else
          ((float*)Cp)[sC * b + (long)(row + j) * ldc + col] = acc[fm][fn][j];
      }
    }
  }
}

extern "C" void kernel_launch(void* const* d_in, const int* in_sizes, int n_in,
                              void* d_out, int out_size, void* d_ws, size_t ws_size,
                              hipStream_t stream) {
  const float* p_enc = (const float*)d_in[0];  // [B, LP, H]
  const float* q_enc = (const float*)d_in[1];  // [B, LQ, H]
  const float* Gw    = (const float*)d_in[2];  // [H, H]
  const float* Gb    = (const float*)d_in[3];  // [H]
  float* m_p = (float*)d_out;                  // [B, LP, H]
  float* m_q = m_p + (long)BB * LP * HH;       // [B, LQ, H]

  // workspace carve (~322 MB); pT16 aliases att (att dead after P_q built)
  half_t* w16     = (half_t*)d_ws;                      // H*H
  half_t* qproj16 = w16 + (long)HH * HH;                // B*LQ*H
  half_t* qT16    = qproj16 + (long)BB * LQ * HH;       // B*H*LQ
  half_t* Pp      = qT16 + (long)BB * HH * LQ;          // B*LP*LQ
  half_t* Pq      = Pp + (long)BB * LP * LQ;            // B*LQ*LP
  float*  cmaxb   = (float*)(Pq + (long)BB * LQ * LP);  // B*LQ
  float*  cinvb   = cmaxb + (long)BB * LQ;              // B*LQ
  float*  att     = cinvb + (long)BB * LQ;              // B*LP*LQ f32
  half_t* pT16    = (half_t*)att;                       // alias: B*H*LP

  cvt_w_k<<<HH * HH / 1024, 256, 0, stream>>>(Gw, w16);

  // qT16[b][h][q] = (f16) q_enc[b][q][h]
  tr_cvt_k<false><<<dim3(HH / 64, LQ / 64, BB), 256, 0, stream>>>(
      q_enc, qT16, nullptr, nullptr, LQ, HH);

  // qproj16[bq][o] = q_enc[bq,:] . Gw[o,:] + Gb[o]
  gemm_k<M_QPROJ><<<dim3(HH / 128, BB * LQ / 128, 1), 256, 0, stream>>>(
      q_enc, w16, qproj16, Gb, HH, HH, HH, HH, 0, 0, 0);

  // att[b][p][q] = p_enc[b,p,:] . qproj[b,q,:]
  gemm_k<M_ATT><<<dim3(LQ / 128, LP / 128, BB), 256, 0, stream>>>(
      p_enc, qproj16, att, nullptr, HH, HH, LQ, HH,
      (long)LP * HH, (long)LQ * HH, (long)LP * LQ);

  // P_p = row-softmax(att) as f16
  rownorm_k<2><<<BB * LP / 4, 256, 0, stream>>>(att, Pp);

  // col stats + P_q = col-softmax(att)^T as f16
  cstats_k<<<dim3(LQ / 64, BB), 256, 0, stream>>>(att, cmaxb, cinvb);
  tr_cvt_k<true><<<dim3(LQ / 64, LP / 64, BB), 256, 0, stream>>>(
      att, Pq, cmaxb, cinvb, LP, LQ);

  // pT16[b][h][p] = (f16) p_enc[b][p][h]   (overwrites att)
  tr_cvt_k<false><<<dim3(HH / 64, LP / 64, BB), 256, 0, stream>>>(
      p_enc, pT16, nullptr, nullptr, LP, HH);

  // m_p = P_p @ q_enc   (M=LP, N=H, K=LQ)
  gemm_k<M_F16><<<dim3(HH / 128, LP / 128, BB), 256, 0, stream>>>(
      Pp, qT16, m_p, nullptr, LQ, LQ, HH, LQ,
      (long)LP * LQ, (long)HH * LQ, (long)LP * HH);

  // m_q = P_q @ p_enc   (M=LQ, N=H, K=LP)
  gemm_k<M_F16><<<dim3(HH / 128, LQ / 128, BB), 256, 0, stream>>>(
      Pq, pT16, m_q, nullptr, LP, LP, HH, LP,
      (long)LQ * LP, (long)HH * LP, (long)LQ * HH);
}

// Round 3
// 662.819 us; speedup vs baseline: 1.4484x; 1.3741x over previous
//
#include <hip/hip_runtime.h>

typedef _Float16 half_t;
typedef _Float16 f16x8 __attribute__((ext_vector_type(8)));
typedef _Float16 f16x4 __attribute__((ext_vector_type(4)));
typedef float    f32x4 __attribute__((ext_vector_type(4)));

#define BB 32
#define LP 2048
#define LQ 512
#define HH 1024

enum { M_QPROJ = 0, M_ATT = 1, M_F16 = 2 };

// ---------------- W f32 -> f16 ----------------
__global__ void cvt_w_k(const float* __restrict__ w, half_t* __restrict__ o) {
  long i = ((long)blockIdx.x * 256 + threadIdx.x) * 4;
  f32x4 v = *(const f32x4*)(w + i);
  f16x4 h;
  h[0] = (half_t)v[0]; h[1] = (half_t)v[1]; h[2] = (half_t)v[2]; h[3] = (half_t)v[3];
  *(f16x4*)(o + i) = h;
}

// ---------------- tiled transpose + cvt (+optional col-exp) ----------------
template<bool EXP>
__global__ __launch_bounds__(256) void tr_cvt_k(const float* __restrict__ in,
                                                half_t* __restrict__ out,
                                                const float* __restrict__ smax,
                                                const float* __restrict__ sinv,
                                                int R, int C) {
  __shared__ half_t tile[64 * 64];
  const long zb = blockIdx.z;
  const float* src = in + zb * (long)R * C;
  half_t* dst = out + zb * (long)C * R;
  const int r0 = blockIdx.y * 64, c0 = blockIdx.x * 64;
  const int t = threadIdx.x;
  const int cl = (t & 15) * 4;
  const int rl = t >> 4;

  float cm[4], ci[4];
  if constexpr (EXP) {
    f32x4 a = *(const f32x4*)(smax + zb * C + c0 + cl);
    f32x4 bvec = *(const f32x4*)(sinv + zb * C + c0 + cl);
#pragma unroll
    for (int j = 0; j < 4; j++) { cm[j] = a[j]; ci[j] = bvec[j]; }
  }
#pragma unroll
  for (int rr = 0; rr < 4; rr++) {
    int r = rr * 16 + rl;
    f32x4 v = *(const f32x4*)(src + (long)(r0 + r) * C + c0 + cl);
#pragma unroll
    for (int j = 0; j < 4; j++) {
      float x = v[j];
      if constexpr (EXP) x = __expf(x - cm[j]) * ci[j];
      int c = cl + j;
      tile[c * 64 + (r ^ (((c >> 3) & 7) << 3))] = (half_t)x;
    }
  }
  __syncthreads();
  const int c = t >> 2;
  const int rch = (t & 3) * 16;
  const int m = (c >> 3) & 7;
  const int B0 = c * 64 + (rch ^ ((m << 3) & 48));
  const int hi = (m & 1) << 3;
  f16x8 g0 = *(const f16x8*)&tile[B0 + hi];
  f16x8 g1 = *(const f16x8*)&tile[B0 + (8 ^ hi)];
  half_t* dp = dst + (long)(c0 + c) * R + r0 + rch;
  *(f16x8*)dp = g0;
  *(f16x8*)(dp + 8) = g1;
}

// ---------------- fused row softmax + normalize -> f16 ----------------
template<int NV>
__global__ __launch_bounds__(256) void rownorm_k(const float* __restrict__ in,
                                                 half_t* __restrict__ out) {
  const int lane = threadIdx.x & 63;
  const long row = (long)blockIdx.x * 4 + (threadIdx.x >> 6);
  const int L = NV * 256;
  const float* src = in + row * L;
  f32x4 v[NV];
#pragma unroll
  for (int i = 0; i < NV; i++) v[i] = *(const f32x4*)(src + i * 256 + lane * 4);
  float m = -3e38f;
#pragma unroll
  for (int i = 0; i < NV; i++)
    m = fmaxf(m, fmaxf(fmaxf(v[i][0], v[i][1]), fmaxf(v[i][2], v[i][3])));
#pragma unroll
  for (int o = 32; o > 0; o >>= 1) m = fmaxf(m, __shfl_xor(m, o, 64));
  float s = 0.f;
#pragma unroll
  for (int i = 0; i < NV; i++)
#pragma unroll
    for (int j = 0; j < 4; j++) { v[i][j] = __expf(v[i][j] - m); s += v[i][j]; }
#pragma unroll
  for (int o = 32; o > 0; o >>= 1) s += __shfl_xor(s, o, 64);
  const float inv = 1.f / s;
  half_t* dst = out + row * L;
#pragma unroll
  for (int i = 0; i < NV; i++) {
    f16x4 h;
#pragma unroll
    for (int j = 0; j < 4; j++) h[j] = (half_t)(v[i][j] * inv);
    *(f16x4*)(dst + i * 256 + lane * 4) = h;
  }
}

// ---------------- finalize col stats from 16 per-m-tile partials ----------------
__global__ __launch_bounds__(256) void cfin_k(const float* __restrict__ pmg,
                                              const float* __restrict__ psg,
                                              float* __restrict__ cmax,
                                              float* __restrict__ cinv) {
  long i = (long)blockIdx.x * 256 + threadIdx.x;  // b*LQ + q
  long b = i / LQ, q = i - b * LQ;
  const float* mp = pmg + (b * 16) * LQ + q;
  const float* sp = psg + (b * 16) * LQ + q;
  float m = -3e38f, s = 0.f;
#pragma unroll
  for (int t = 0; t < 16; t++) {
    float mm = mp[(long)t * LQ], ss = sp[(long)t * LQ];
    float nm = fmaxf(m, mm);
    s = s * __expf(m - nm) + ss * __expf(mm - nm);
    m = nm;
  }
  cmax[i] = m;
  cinv[i] = 1.f / s;
}

// ---------------- unified TN MFMA GEMM, 128x128 tile, BK=32 ----------------
// XCD chunked-swizzled block ids. M_ATT additionally emits per-tile column
// softmax partials (max,sum over the tile's 128 rows) to pmg/psg[b][mt][LQ].
template<int MODE>
__global__ __launch_bounds__(256) void gemm_k(
    const void* __restrict__ Ap, const half_t* __restrict__ Bp, void* __restrict__ Cp,
    const float* __restrict__ bias,
    float* __restrict__ pmg, float* __restrict__ psg,
    int lda, int ldb, int ldc, int K,
    long sA, long sB, long sC) {
  __shared__ __align__(16) half_t As[128][40];
  __shared__ __align__(16) half_t Bs[128][40];

  // ---- bijective XCD chunked swizzle (m204) ----
  const int nbx = gridDim.x, nby = gridDim.y;
  const long nwg = (long)nbx * nby * gridDim.z;
  long lid = blockIdx.x + (long)nbx * (blockIdx.y + (long)nby * blockIdx.z);
  {
    const long q8 = nwg >> 3, r8 = nwg & 7;
    const long xcd = lid & 7, rest = lid >> 3;
    lid = (xcd < r8 ? xcd * (q8 + 1) : r8 * (q8 + 1) + (xcd - r8) * q8) + rest;
  }
  const int bx = (int)(lid % nbx);
  const long tmp = lid / nbx;
  const int by = (int)(tmp % nby);
  const int bz = (int)(tmp / nby);

  const int t = threadIdx.x;
  const int lane = t & 63;
  const int wid = t >> 6;
  const int wm = (wid >> 1) * 64, wn = (wid & 1) * 64;
  const int m0 = by * 128, n0 = bx * 128;

  f32x4 acc[4][4] = {};

  const int s_row = t >> 2, s_kq = (t & 3) * 8;  // f16 stage
  const int f_row = t >> 3, f_c  = (t & 7) * 4;  // f32 stage

  const half_t* A16 = (const half_t*)Ap + sA * bz;
  const float*  A32 = (const float*)Ap  + sA * bz;
  const half_t* B16 = Bp + sB * bz;

  const int fr = lane & 15, fg = (lane >> 4) * 8;

  for (int k0 = 0; k0 < K; k0 += 32) {
    if constexpr (MODE == M_F16) {
#pragma unroll
      for (int p = 0; p < 128; p += 64) {
        int row = s_row + p;
        *(f16x8*)&As[row][s_kq] =
            *(const f16x8*)(A16 + (long)(m0 + row) * lda + k0 + s_kq);
      }
    } else {
#pragma unroll
      for (int p = 0; p < 128; p += 32) {
        int row = f_row + p;
        f32x4 v = *(const f32x4*)(A32 + (long)(m0 + row) * lda + k0 + f_c);
        f16x4 h;
        h[0] = (half_t)v[0]; h[1] = (half_t)v[1];
        h[2] = (half_t)v[2]; h[3] = (half_t)v[3];
        *(f16x4*)&As[row][f_c] = h;
      }
    }
#pragma unroll
    for (int p = 0; p < 128; p += 64) {
      int row = s_row + p;
      *(f16x8*)&Bs[row][s_kq] =
          *(const f16x8*)(B16 + (long)(n0 + row) * ldb + k0 + s_kq);
    }
    __syncthreads();

    f16x8 af[4], bf[4];
#pragma unroll
    for (int f = 0; f < 4; f++) af[f] = *(const f16x8*)&As[wm + f * 16 + fr][fg];
#pragma unroll
    for (int f = 0; f < 4; f++) bf[f] = *(const f16x8*)&Bs[wn + f * 16 + fr][fg];
#pragma unroll
    for (int fm = 0; fm < 4; fm++)
#pragma unroll
      for (int fn = 0; fn < 4; fn++)
        acc[fm][fn] = __builtin_amdgcn_mfma_f32_16x16x32_f16(af[fm], bf[fn], acc[fm][fn], 0, 0, 0);
    __syncthreads();
  }

  // ---- epilogue: D row=(lane>>4)*4+j, col=lane&15 ----
  const int r0 = (lane >> 4) * 4;
#pragma unroll
  for (int fn = 0; fn < 4; fn++) {
    int col = n0 + wn + fn * 16 + fr;
    float bv = 0.f;
    if constexpr (MODE == M_QPROJ) bv = bias[col];
#pragma unroll
    for (int fm = 0; fm < 4; fm++) {
      int row = m0 + wm + fm * 16 + r0;
#pragma unroll
      for (int j = 0; j < 4; j++) {
        if constexpr (MODE == M_QPROJ)
          ((half_t*)Cp)[(long)(row + j) * ldc + col] = (half_t)(acc[fm][fn][j] + bv);
        else
          ((float*)Cp)[sC * bz + (long)(row + j) * ldc + col] = acc[fm][fn][j];
      }
    }
  }

  // ---- M_ATT: per-tile column softmax partials over 128 rows ----
  if constexpr (MODE == M_ATT) {
    __shared__ float pmL[4][128], psL[4][128];
    float cm4[4], cs4[4];
#pragma unroll
    for (int fn = 0; fn < 4; fn++) {
      float m = acc[0][fn][0];
#pragma unroll
      for (int fm = 0; fm < 4; fm++)
#pragma unroll
        for (int j = 0; j < 4; j++) m = fmaxf(m, acc[fm][fn][j]);
      float s = 0.f;
#pragma unroll
      for (int fm = 0; fm < 4; fm++)
#pragma unroll
        for (int j = 0; j < 4; j++) s += __expf(acc[fm][fn][j] - m);
      cm4[fn] = m; cs4[fn] = s;
    }
    // reduce across the 4 lane-groups (lanes 16/32 apart share a column)
#pragma unroll
    for (int off = 16; off < 64; off <<= 1) {
#pragma unroll
      for (int fn = 0; fn < 4; fn++) {
        float om = __shfl_xor(cm4[fn], off, 64);
        float os = __shfl_xor(cs4[fn], off, 64);
        float nm = fmaxf(cm4[fn], om);
        cs4[fn] = cs4[fn] * __expf(cm4[fn] - nm) + os * __expf(om - nm);
        cm4[fn] = nm;
      }
    }
    if (lane < 16) {
#pragma unroll
      for (int fn = 0; fn < 4; fn++) {
        pmL[wid][wn + fn * 16 + lane] = cm4[fn];
        psL[wid][wn + fn * 16 + lane] = cs4[fn];
      }
    }
    __syncthreads();
    if (t < 128) {
      const int wi = t >> 6;  // cols 0-63: waves 0,2 ; cols 64-127: waves 1,3
      float m1 = pmL[wi][t], m2 = pmL[wi + 2][t];
      float s1 = psL[wi][t], s2 = psL[wi + 2][t];
      float nm = fmaxf(m1, m2);
      float s = s1 * __expf(m1 - nm) + s2 * __expf(m2 - nm);
      long idx = ((long)bz * nby + by) * ldc + n0 + t;
      pmg[idx] = nm;
      psg[idx] = s;
    }
  }
}

extern "C" void kernel_launch(void* const* d_in, const int* in_sizes, int n_in,
                              void* d_out, int out_size, void* d_ws, size_t ws_size,
                              hipStream_t stream) {
  const float* p_enc = (const float*)d_in[0];  // [B, LP, H]
  const float* q_enc = (const float*)d_in[1];  // [B, LQ, H]
  const float* Gw    = (const float*)d_in[2];  // [H, H]
  const float* Gb    = (const float*)d_in[3];  // [H]
  float* m_p = (float*)d_out;
  float* m_q = m_p + (long)BB * LP * HH;

  // workspace carve (~341 MB); pT16 aliases att (att dead after P_q built)
  half_t* w16     = (half_t*)d_ws;                      // H*H
  half_t* qproj16 = w16 + (long)HH * HH;                // B*LQ*H
  half_t* qT16    = qproj16 + (long)BB * LQ * HH;       // B*H*LQ
  half_t* Pp      = qT16 + (long)BB * HH * LQ;          // B*LP*LQ
  half_t* Pq      = Pp + (long)BB * LP * LQ;            // B*LQ*LP
  float*  cmaxb   = (float*)(Pq + (long)BB * LQ * LP);  // B*LQ
  float*  cinvb   = cmaxb + (long)BB * LQ;              // B*LQ
  float*  pmg     = cinvb + (long)BB * LQ;              // B*16*LQ
  float*  psg     = pmg + (long)BB * 16 * LQ;           // B*16*LQ
  float*  att     = psg + (long)BB * 16 * LQ;           // B*LP*LQ f32
  half_t* pT16    = (half_t*)att;                       // alias: B*H*LP

  cvt_w_k<<<HH * HH / 1024, 256, 0, stream>>>(Gw, w16);

  // qT16[b][h][q] = (f16) q_enc[b][q][h]
  tr_cvt_k<false><<<dim3(HH / 64, LQ / 64, BB), 256, 0, stream>>>(
      q_enc, qT16, nullptr, nullptr, LQ, HH);

  // qproj16[bq][o] = q_enc[bq,:] . Gw[o,:] + Gb[o]
  gemm_k<M_QPROJ><<<dim3(HH / 128, BB * LQ / 128, 1), 256, 0, stream>>>(
      q_enc, w16, qproj16, Gb, nullptr, nullptr, HH, HH, HH, HH, 0, 0, 0);

  // att[b][p][q] = p_enc[b,p,:] . qproj[b,q,:]  (+ fused col-stat partials)
  gemm_k<M_ATT><<<dim3(LQ / 128, LP / 128, BB), 256, 0, stream>>>(
      p_enc, qproj16, att, nullptr, pmg, psg, HH, HH, LQ, HH,
      (long)LP * HH, (long)LQ * HH, (long)LP * LQ);

  // P_p = row-softmax(att) as f16
  rownorm_k<2><<<BB * LP / 4, 256, 0, stream>>>(att, Pp);

  // finalize col stats, then P_q = col-softmax(att)^T as f16
  cfin_k<<<BB * LQ / 256, 256, 0, stream>>>(pmg, psg, cmaxb, cinvb);
  tr_cvt_k<true><<<dim3(LQ / 64, LP / 64, BB), 256, 0, stream>>>(
      att, Pq, cmaxb, cinvb, LP, LQ);

  // pT16[b][h][p] = (f16) p_enc[b][p][h]   (overwrites att)
  tr_cvt_k<false><<<dim3(HH / 64, LP / 64, BB), 256, 0, stream>>>(
      p_enc, pT16, nullptr, nullptr, LP, HH);

  // m_p = P_p @ q_enc^T16   (M=LP, N=H, K=LQ)
  gemm_k<M_F16><<<dim3(HH / 128, LP / 128, BB), 256, 0, stream>>>(
      Pp, qT16, m_p, nullptr, nullptr, nullptr, LQ, LQ, HH, LQ,
      (long)LP * LQ, (long)HH * LQ, (long)LP * HH);

  // m_q = P_q @ p_enc^T16   (M=LQ, N=H, K=LP)
  gemm_k<M_F16><<<dim3(HH / 128, LQ / 128, BB), 256, 0, stream>>>(
      Pq, pT16, m_q, nullptr, nullptr, nullptr, LP, LP, HH, LP,
      (long)LQ * LP, (long)HH * LP, (long)LQ * HH);
}